// Round 13
// baseline (722.461 us; speedup 1.0000x reference)
//
#include <hip/hip_runtime.h>
#include <hip/hip_fp16.h>

typedef _Float16 f16_t;
typedef _Float16 f16x8 __attribute__((ext_vector_type(8)));
typedef float f32x4 __attribute__((ext_vector_type(4)));

#define N_NODES 50000
#define N_EDGES 800000
#define C 64
#define N_GRAPHS 64

#define NBKT 782                   // buckets == 64-node GEMM tiles (dst >> 6)
#define BKT_CAP 1536               // slots per bucket (mean 1024 + 16 sigma)
#define HS_BLOCKS 256              // hist+scatter grid
#define HS_EPB (N_EDGES / HS_BLOCKS)   // 3125 (exact)
#define CAST_BLKS 1563             // ceil(400000/256)
#define CUR_STRIDE 16              // pad cursors to one 64B line each

// ---------------- workspace layout (bytes; ws ~256 MB) ----------------
#define OFF_CUR    0u          // NBKT cursors, padded x16 ints (~50 KB)
#define OFF_POOLED 51200u      // N_GRAPHS*2 uints
#define OFF_DONE   51712u      // completion counter
#define OFF_EPK    52224u      // NBKT*BKT_CAP ints (~4.8 MB): src | dl<<16
#define OFF_XH     4857088u    // x fp16 (6.4 MB)
#define OFF_H1H    11257344u   // h1 fp16 (6.4 MB)
#define OFF_WT1    17657600u   // Wcat1^T fp16 (16 KB)
#define OFF_WT2    17673984u   // Wcat2^T fp16 (16 KB)
// total ~17.7 MB

__device__ __forceinline__ unsigned pack2h(float x, float y) {
    __half2 h = __floats2half2_rn(x, y);
    return *reinterpret_cast<unsigned*>(&h);
}

// ---------------- k0: init (block 0) + x->fp16 cast + W transpose/cast ----------------
__global__ __launch_bounds__(256) void init_cast_wcast_kernel(
        const float* __restrict__ x, f16_t* __restrict__ xh,
        const float* __restrict__ W1r, const float* __restrict__ W1l, f16_t* __restrict__ Wt1,
        const float* __restrict__ W2r, const float* __restrict__ W2l, f16_t* __restrict__ Wt2,
        int* __restrict__ cur, unsigned int* __restrict__ pooled,
        unsigned int* __restrict__ done_cnt) {
    __shared__ float w0[64 * 64];
    __shared__ float w1[64 * 64];
    const int blk = blockIdx.x;
    const int t = threadIdx.x;
    if (blk < CAST_BLKS) {
        if (blk == 0) {
            for (int i = t; i < NBKT * CUR_STRIDE; i += 256) cur[i] = 0;
            if (t < N_GRAPHS * 2) pooled[t] = 0u;
            if (t == 0) *done_cnt = 0u;
        }
        const int i = blk * 256 + t;
        if (i < N_NODES * C / 8) {
            const float4* p = (const float4*)(x + (size_t)i * 8);
            float4 a = p[0], b = p[1];
            uint4 w;
            w.x = pack2h(a.x, a.y);
            w.y = pack2h(a.z, a.w);
            w.z = pack2h(b.x, b.y);
            w.w = pack2h(b.z, b.w);
            *(uint4*)(xh + (size_t)i * 8) = w;
        }
    } else {
        const int which = blk - CAST_BLKS;   // 0 or 1
        const float* Wr = which ? W2r : W1r;
        const float* Wl = which ? W2l : W1l;
        f16_t* Wt = which ? Wt2 : Wt1;
        for (int i = t * 4; i < 4096; i += 1024) {
            *(float4*)&w0[i] = *(const float4*)&Wr[i];
            *(float4*)&w1[i] = *(const float4*)&Wl[i];
        }
        __syncthreads();
        const int n = t >> 2, q = t & 3;
        for (int kk = q * 32; kk < q * 32 + 32; kk++) {
            float v = (kk < 64) ? w0[kk * 64 + n] : w1[(kk - 64) * 64 + n];
            Wt[n * 128 + kk] = (f16_t)v;
        }
    }
}

// ---------------- k1: fused hist + reserve + scatter into 64-node buckets ----------------
__global__ __launch_bounds__(256) void hist_scatter_kernel(const int* __restrict__ src,
                                                           const int* __restrict__ dst,
                                                           int* __restrict__ cur,
                                                           int* __restrict__ epk) {
    __shared__ int h[NBKT];
    __shared__ int base_s[NBKT];
    const int t = threadIdx.x;
    const int blk = blockIdx.x;
    for (int i = t; i < NBKT; i += 256) h[i] = 0;
    __syncthreads();
    const int beg = blk * HS_EPB;
    for (int i = beg + t; i < beg + HS_EPB; i += 256)
        atomicAdd(&h[dst[i] >> 6], 1);
    __syncthreads();
    for (int b = t; b < NBKT; b += 256) {
        int hv = h[b];
        int old = hv ? atomicAdd(&cur[b * CUR_STRIDE], hv) : 0;
        base_s[b] = b * BKT_CAP + old;
        h[b] = 0;   // reuse as local cursor
    }
    __syncthreads();
    for (int i = beg + t; i < beg + HS_EPB; i += 256) {
        int d = dst[i];
        int b = d >> 6;
        int off = atomicAdd(&h[b], 1);
        int pos = base_s[b] + off;
        if (pos < (b + 1) * BKT_CAP)   // statistically unreachable guard
            epk[pos] = src[i] | ((d & 63) << 16);
    }
}

// ======== fused edge-parallel agg (LDS fp32 atomics) + staging + MFMA ========
// Block = bucket = 64 nodes, 1024 threads = 16 waves. Edge e handled by
// (wave wv, slot s): lane(s,j) gathers 8B chunk j of src row, ds_add into
// aggL[dl][4j..4j+3]. Iterations independent; 2-deep software pipeline.
__device__ __forceinline__ void agg_stage_mfma(
        const f16_t* __restrict__ Hsrc,
        const int* __restrict__ epk, int n_edges,
        const f16_t* __restrict__ Wt, const float* __restrict__ bias,
        f16_t* Als, f16_t* Wls, float* aggL,
        int row0, int t, f32x4& acc, int& ncol, int& outrow0) {
    const int cr = t >> 4, cj = t & 15;   // staging/conversion mapping
    int gxr = row0 + cr; if (gxr > N_NODES - 1) gxr = N_NODES - 1;
    uint2 xv = *(const uint2*)(Hsrc + (size_t)gxr * 64 + cj * 4);     // A-operand row chunk
    uint4 wvv = *(const uint4*)(Wt + cr * 128 + cj * 8);              // W chunk
    // zero accumulator
    for (int i = t; i < 64 * 65; i += 1024) aggL[i] = 0.f;
    __syncthreads();
    // edge-parallel gather + LDS atomic accumulate (2-deep pipeline)
    {
        const int wv = t >> 6, lane = t & 63;
        const int slot = lane >> 4, j = lane & 15;
        const uint2* hw = (const uint2*)Hsrc;
        int e = wv * 4 + slot;
        int pk0 = (e < n_edges) ? epk[e] : -1;
        int pk1 = (e + 64 < n_edges) ? epk[e + 64] : -1;
        while (pk0 >= 0) {
            int ne = e + 128;
            int npk0 = (ne < n_edges) ? epk[ne] : -1;
            int npk1 = (ne + 64 < n_edges) ? epk[ne + 64] : -1;
            {
                uint2 u = hw[(size_t)(pk0 & 0xFFFF) * 16 + j];
                float2 a = __half22float2(*(__half2*)&u.x);
                float2 b = __half22float2(*(__half2*)&u.y);
                float* p = &aggL[(pk0 >> 16) * 65 + j * 4];
                atomicAdd(p + 0, a.x); atomicAdd(p + 1, a.y);
                atomicAdd(p + 2, b.x); atomicAdd(p + 3, b.y);
            }
            if (pk1 >= 0) {
                uint2 u = hw[(size_t)(pk1 & 0xFFFF) * 16 + j];
                float2 a = __half22float2(*(__half2*)&u.x);
                float2 b = __half22float2(*(__half2*)&u.y);
                float* p = &aggL[(pk1 >> 16) * 65 + j * 4];
                atomicAdd(p + 0, a.x); atomicAdd(p + 1, a.y);
                atomicAdd(p + 2, b.x); atomicAdd(p + 3, b.y);
            }
            e = ne; pk0 = npk0; pk1 = npk1;
        }
    }
    __syncthreads();
    // convert agg -> fp16 into k=64..127 half of Als; store x/W halves
    {
        float f0 = aggL[cr * 65 + cj * 4 + 0];
        float f1 = aggL[cr * 65 + cj * 4 + 1];
        float f2 = aggL[cr * 65 + cj * 4 + 2];
        float f3 = aggL[cr * 65 + cj * 4 + 3];
        uint2 o; o.x = pack2h(f0, f1); o.y = pack2h(f2, f3);
        *(uint2*)((char*)Als + cr * 256 + ((128 + cj * 8) ^ ((cr & 7) << 4))) = o;
        *(uint2*)((char*)Als + cr * 256 + ((cj * 8) ^ ((cr & 7) << 4))) = xv;
        *(uint4*)((char*)Wls + cr * 256 + ((cj * 16) ^ ((cr & 7) << 4))) = wvv;
    }
    __syncthreads();
    // MFMA: wave wv -> (wr, wc) 16x16 tile, k = 128
    const int wv = t >> 6, lane = t & 63;
    const int lr = lane & 15, kh = lane >> 4;
    const int wr = wv >> 2, wc = wv & 3;
    const int arow = wr * 16 + lr;
    ncol = wc * 16 + lr;
    outrow0 = row0 + wr * 16 + kh * 4;
    float bv = bias[ncol];
    acc = (f32x4){bv, bv, bv, bv};
    #pragma unroll
    for (int kt = 0; kt < 4; kt++) {
        const int kb = (kt * 32 + kh * 8) * 2;
        f16x8 a = *(const f16x8*)((const char*)Als + arow * 256 + (kb ^ ((arow & 7) << 4)));
        f16x8 b = *(const f16x8*)((const char*)Wls + ncol * 256 + (kb ^ ((ncol & 7) << 4)));
        acc = __builtin_amdgcn_mfma_f32_16x16x32_f16(a, b, acc, 0, 0, 0);
    }
}

// ---------------- layer 1: fused agg + GEMM -> h1 fp16 ----------------
__global__ __launch_bounds__(1024) void layer1_kernel(const f16_t* __restrict__ xh,
                                                      const int* __restrict__ epk,
                                                      const int* __restrict__ cur,
                                                      const f16_t* __restrict__ Wt,
                                                      const float* __restrict__ bias,
                                                      f16_t* __restrict__ h1h) {
    __shared__ f16_t Als[64 * 128];
    __shared__ f16_t Wls[64 * 128];
    __shared__ float aggL[64 * 65];
    const int t = threadIdx.x;
    const int blk = blockIdx.x;
    const int row0 = blk * 64;
    int n = cur[blk * CUR_STRIDE]; if (n > BKT_CAP) n = BKT_CAP;
    f32x4 acc; int ncol, outrow0;
    agg_stage_mfma(xh, epk + (size_t)blk * BKT_CAP, n, Wt, bias,
                   Als, Wls, aggL, row0, t, acc, ncol, outrow0);
    #pragma unroll
    for (int rr = 0; rr < 4; rr++) {
        const int gm = outrow0 + rr;
        if (gm < N_NODES)
            h1h[(size_t)gm * 64 + ncol] = (f16_t)fmaxf(acc[rr], 0.f);
    }
}

// ---------------- layer 2: fused agg + GEMM + head + pooling + final ----------------
__global__ __launch_bounds__(1024) void layer2_head_kernel(
        const f16_t* __restrict__ h1h,
        const int* __restrict__ epk, const int* __restrict__ cur,
        const f16_t* __restrict__ Wt, const float* __restrict__ bias,
        const int* __restrict__ batch,
        const float* __restrict__ fc1w, const float* __restrict__ fc1b,
        const float* __restrict__ fc2w, const float* __restrict__ fc2b,
        float* __restrict__ mid_out, unsigned int* __restrict__ pooled,
        unsigned int* __restrict__ done_cnt, float* __restrict__ fin_out) {
    __shared__ f16_t Als[64 * 128];
    __shared__ f16_t Wls[64 * 128];
    __shared__ float aggL[64 * 65];   // reused as h2 tile after MFMA
    __shared__ float w1s[512];
    __shared__ float z1s[64 * 9];
    __shared__ float b1s[8];
    __shared__ float w2s[16];
    __shared__ float b2s[2];
    __shared__ unsigned int pool_s[N_GRAPHS * 2];
    __shared__ unsigned int amLast;
    __shared__ float fin[N_GRAPHS * 2];
    const int t = threadIdx.x;
    const int blk = blockIdx.x;
    const int row0 = blk * 64;
    if (t < 512) w1s[t] = fc1w[t];
    if (t >= 512 && t < 520) b1s[t - 512] = fc1b[t - 512];
    if (t >= 520 && t < 536) w2s[t - 520] = fc2w[t - 520];
    if (t >= 536 && t < 538) b2s[t - 536] = fc2b[t - 536];
    if (t >= 544 && t < 544 + N_GRAPHS * 2) pool_s[t - 544] = 0u;
    int n = cur[blk * CUR_STRIDE]; if (n > BKT_CAP) n = BKT_CAP;
    f32x4 acc; int ncol, outrow0;
    agg_stage_mfma(h1h, epk + (size_t)blk * BKT_CAP, n, Wt, bias,
                   Als, Wls, aggL, row0, t, acc, ncol, outrow0);
    float* tile = aggL;   // aggL dead after conversion; reuse as 64x65 h2 tile
    #pragma unroll
    for (int rr = 0; rr < 4; rr++)
        tile[(outrow0 - row0 + rr) * 65 + ncol] = fmaxf(acc[rr], 0.f);
    __syncthreads();
    const int row = t & 63, qq = t >> 6;
    const int gm = row0 + row;
    const bool valid = gm < N_NODES;
    if (qq < 4) {
        float z0 = b1s[2 * qq], z1v = b1s[2 * qq + 1];
        for (int k = 0; k < 64; k++) {
            float a = tile[row * 65 + k];
            z0  += a * w1s[k * 8 + 2 * qq];
            z1v += a * w1s[k * 8 + 2 * qq + 1];
        }
        z1s[row * 9 + 2 * qq]     = fmaxf(z0, 0.f);
        z1s[row * 9 + 2 * qq + 1] = fmaxf(z1v, 0.f);
    }
    if (qq == 4 && valid) {   // mid softmax (wave group 4, overlaps fc1)
        float rv[8];
        #pragma unroll
        for (int c = 0; c < 8; c++) rv[c] = tile[row * 65 + c];
        float m = rv[0];
        #pragma unroll
        for (int c = 1; c < 8; c++) m = fmaxf(m, rv[c]);
        float ex[8], s = 0.f;
        #pragma unroll
        for (int c = 0; c < 8; c++) { ex[c] = __expf(rv[c] - m); s += ex[c]; }
        float inv = 1.f / s;
        float4 v0 = {ex[0] * inv, ex[1] * inv, ex[2] * inv, ex[3] * inv};
        float4 v1 = {ex[4] * inv, ex[5] * inv, ex[6] * inv, ex[7] * inv};
        *(float4*)&mid_out[(size_t)gm * 8]     = v0;
        *(float4*)&mid_out[(size_t)gm * 8 + 4] = v1;
    }
    __syncthreads();
    if (qq == 0 && valid) {   // fc2 + LDS pool
        float z20 = b2s[0], z21 = b2s[1];
        #pragma unroll
        for (int o = 0; o < 8; o++) {
            float z = z1s[row * 9 + o];
            z20 += z * w2s[o * 2];
            z21 += z * w2s[o * 2 + 1];
        }
        z20 = fmaxf(z20, 0.f);
        z21 = fmaxf(z21, 0.f);
        int b = batch[gm];
        atomicMax(&pool_s[b * 2 + 0], __float_as_uint(z20));
        atomicMax(&pool_s[b * 2 + 1], __float_as_uint(z21));
    }
    __syncthreads();
    if (t < N_GRAPHS * 2) {
        unsigned int v = pool_s[t];
        if (v) atomicMax(&pooled[t], v);
    }
    __syncthreads();
    if (t == 0) {
        __threadfence();
        unsigned int prev = atomicAdd(done_cnt, 1u);
        amLast = (prev == gridDim.x - 1) ? 1u : 0u;
    }
    __syncthreads();
    if (amLast) {
        if (t < N_GRAPHS * 2) fin[t] = __uint_as_float(atomicMax(&pooled[t], 0u));
        __syncthreads();
        if (t < N_GRAPHS) {
            float v0 = fin[2 * t], v1 = fin[2 * t + 1];
            float m = fmaxf(v0, v1);
            float e0 = __expf(v0 - m), e1 = __expf(v1 - m);
            float s = e0 + e1;
            fin_out[2 * t]     = e0 / s;
            fin_out[2 * t + 1] = e1 / s;
        }
    }
}

// ---------------- launch ----------------
extern "C" void kernel_launch(void* const* d_in, const int* in_sizes, int n_in,
                              void* d_out, int out_size, void* d_ws, size_t ws_size,
                              hipStream_t stream) {
    const float* x    = (const float*)d_in[0];
    const int*   ei   = (const int*)d_in[1];
    const int*   batch= (const int*)d_in[2];
    const float* W1r  = (const float*)d_in[3];
    const float* W1l  = (const float*)d_in[4];
    const float* b1   = (const float*)d_in[5];
    const float* W2r  = (const float*)d_in[6];
    const float* W2l  = (const float*)d_in[7];
    const float* b2   = (const float*)d_in[8];
    const float* fc1w = (const float*)d_in[9];
    const float* fc1b = (const float*)d_in[10];
    const float* fc2w = (const float*)d_in[11];
    const float* fc2b = (const float*)d_in[12];

    const int* src = ei;
    const int* dst = ei + N_EDGES;

    char* ws = (char*)d_ws;
    int*    cur    = (int*)(ws + OFF_CUR);
    unsigned int* pooled   = (unsigned int*)(ws + OFF_POOLED);
    unsigned int* done_cnt = (unsigned int*)(ws + OFF_DONE);
    int*    epk    = (int*)(ws + OFF_EPK);
    f16_t*  xh     = (f16_t*)(ws + OFF_XH);
    f16_t*  h1h    = (f16_t*)(ws + OFF_H1H);
    f16_t*  Wt1    = (f16_t*)(ws + OFF_WT1);
    f16_t*  Wt2    = (f16_t*)(ws + OFF_WT2);

    float* mid_out = (float*)d_out;                       // 50000*8
    float* fin_out = (float*)d_out + (size_t)N_NODES * 8; // 64*2

    init_cast_wcast_kernel<<<CAST_BLKS + 2, 256, 0, stream>>>(
        x, xh, W1r, W1l, Wt1, W2r, W2l, Wt2, cur, pooled, done_cnt);
    hist_scatter_kernel<<<HS_BLOCKS, 256, 0, stream>>>(src, dst, cur, epk);

    layer1_kernel<<<NBKT, 1024, 0, stream>>>(xh, epk, cur, Wt1, b1, h1h);
    layer2_head_kernel<<<NBKT, 1024, 0, stream>>>(h1h, epk, cur, Wt2, b2, batch,
                                                  fc1w, fc1b, fc2w, fc2b,
                                                  mid_out, pooled, done_cnt, fin_out);
}

// Round 14
// 96.830 us; speedup vs baseline: 7.4611x; 7.4611x over previous
//
#include <hip/hip_runtime.h>
#include <hip/hip_fp16.h>

typedef _Float16 f16_t;
typedef _Float16 f16x8 __attribute__((ext_vector_type(8)));
typedef float f32x4 __attribute__((ext_vector_type(4)));

#define N_NODES 50000
#define N_EDGES 800000
#define C 64
#define N_GRAPHS 64

#define NBKT 782                   // buckets == 64-node GEMM tiles (dst >> 6)
#define BKT_CAP 1536               // slots per bucket (mean ~1023 + 16 sigma)
#define HS_BLOCKS 256              // hist+scatter grid
#define HS_EPB (N_EDGES / HS_BLOCKS)   // 3125 (exact)
#define CAST_BLKS 1563             // ceil(400000/256)
#define CUR_STRIDE 16              // pad cursors to one 64B line each

// ---------------- workspace layout (bytes; ws ~256 MB) ----------------
#define OFF_CUR    0u          // NBKT cursors, padded x16 ints (~50 KB)
#define OFF_POOLED 51200u      // N_GRAPHS*2 uints
#define OFF_DONE   51712u      // completion counter
#define OFF_EPK    52224u      // NBKT*BKT_CAP ints (~4.8 MB): src | dl<<16
#define OFF_XH     4857088u    // x fp16 (6.4 MB)
#define OFF_H1H    11257344u   // h1 fp16 (6.4 MB)
#define OFF_WT1    17657600u   // Wcat1^T fp16 (16 KB)
#define OFF_WT2    17673984u   // Wcat2^T fp16 (16 KB)
// total ~17.7 MB

__device__ __forceinline__ unsigned pack2h(float x, float y) {
    __half2 h = __floats2half2_rn(x, y);
    return *reinterpret_cast<unsigned*>(&h);
}

// ---------------- k0: init (block 0) + x->fp16 cast + W transpose/cast ----------------
__global__ __launch_bounds__(256) void init_cast_wcast_kernel(
        const float* __restrict__ x, f16_t* __restrict__ xh,
        const float* __restrict__ W1r, const float* __restrict__ W1l, f16_t* __restrict__ Wt1,
        const float* __restrict__ W2r, const float* __restrict__ W2l, f16_t* __restrict__ Wt2,
        int* __restrict__ cur, unsigned int* __restrict__ pooled,
        unsigned int* __restrict__ done_cnt) {
    __shared__ float w0[64 * 64];
    __shared__ float w1[64 * 64];
    const int blk = blockIdx.x;
    const int t = threadIdx.x;
    if (blk < CAST_BLKS) {
        if (blk == 0) {
            for (int i = t; i < NBKT * CUR_STRIDE; i += 256) cur[i] = 0;
            if (t < N_GRAPHS * 2) pooled[t] = 0u;
            if (t == 0) *done_cnt = 0u;
        }
        const int i = blk * 256 + t;
        if (i < N_NODES * C / 8) {
            const float4* p = (const float4*)(x + (size_t)i * 8);
            float4 a = p[0], b = p[1];
            uint4 w;
            w.x = pack2h(a.x, a.y);
            w.y = pack2h(a.z, a.w);
            w.z = pack2h(b.x, b.y);
            w.w = pack2h(b.z, b.w);
            *(uint4*)(xh + (size_t)i * 8) = w;
        }
    } else {
        const int which = blk - CAST_BLKS;   // 0 or 1
        const float* Wr = which ? W2r : W1r;
        const float* Wl = which ? W2l : W1l;
        f16_t* Wt = which ? Wt2 : Wt1;
        for (int i = t * 4; i < 4096; i += 1024) {
            *(float4*)&w0[i] = *(const float4*)&Wr[i];
            *(float4*)&w1[i] = *(const float4*)&Wl[i];
        }
        __syncthreads();
        const int n = t >> 2, q = t & 3;
        for (int kk = q * 32; kk < q * 32 + 32; kk++) {
            float v = (kk < 64) ? w0[kk * 64 + n] : w1[(kk - 64) * 64 + n];
            Wt[n * 128 + kk] = (f16_t)v;
        }
    }
}

// ---------------- k1: fused hist + reserve + scatter into 64-node buckets ----------------
__global__ __launch_bounds__(256) void hist_scatter_kernel(const int* __restrict__ src,
                                                           const int* __restrict__ dst,
                                                           int* __restrict__ cur,
                                                           int* __restrict__ epk) {
    __shared__ int h[NBKT];
    __shared__ int base_s[NBKT];
    const int t = threadIdx.x;
    const int blk = blockIdx.x;
    for (int i = t; i < NBKT; i += 256) h[i] = 0;
    __syncthreads();
    const int beg = blk * HS_EPB;
    for (int i = beg + t; i < beg + HS_EPB; i += 256)
        atomicAdd(&h[dst[i] >> 6], 1);
    __syncthreads();
    for (int b = t; b < NBKT; b += 256) {
        int hv = h[b];
        int old = hv ? atomicAdd(&cur[b * CUR_STRIDE], hv) : 0;
        base_s[b] = b * BKT_CAP + old;
        h[b] = 0;   // reuse as local cursor
    }
    __syncthreads();
    for (int i = beg + t; i < beg + HS_EPB; i += 256) {
        int d = dst[i];
        int b = d >> 6;
        int off = atomicAdd(&h[b], 1);
        int pos = base_s[b] + off;
        if (pos < (b + 1) * BKT_CAP)   // statistically unreachable guard
            epk[pos] = src[i] | ((d & 63) << 16);
    }
}

// ======== in-LDS edge sort + per-node gather (r12-proven) + staging + MFMA ========
// Block = 64 nodes, 1024 threads = 16 waves. Sort: 64-bin count -> wave-0 shfl
// scan -> place into eb[] (int LDS atomics, the fine_sort pattern). Gather:
// wave wv owns 4 nodes sequentially; 16 lanes x 8B x 4 edge slots, edge ids
// read from LDS (no esrc global round-trip in the dependent chain).
__device__ __forceinline__ void agg_stage_mfma(
        const f16_t* __restrict__ Hsrc,
        const int* __restrict__ epk_blk, int n_edges,
        const f16_t* __restrict__ Wt, const float* __restrict__ bias,
        f16_t* Als, f16_t* Wls, int* eb, int* cnt, int* beg,
        int row0, int t, f32x4& acc, int& ncol, int& outrow0) {
    const int cr = t >> 4, cj = t & 15;
    int gxr = row0 + cr; if (gxr > N_NODES - 1) gxr = N_NODES - 1;
    uint2 xv = *(const uint2*)(Hsrc + (size_t)gxr * 64 + cj * 4);   // A-row chunk (early)
    uint4 wvv = *(const uint4*)(Wt + cr * 128 + cj * 8);            // W chunk (early)
    // ---- sort this block's edges by dst-local ----
    if (t < 64) cnt[t] = 0;
    __syncthreads();
    int pk0 = (t < n_edges) ? epk_blk[t] : -1;                      // <= 2 edges/thread
    int pk1 = (t + 1024 < n_edges) ? epk_blk[t + 1024] : -1;
    if (pk0 >= 0) atomicAdd(&cnt[pk0 >> 16], 1);
    if (pk1 >= 0) atomicAdd(&cnt[pk1 >> 16], 1);
    __syncthreads();
    if (t < 64) {                     // wave-0 exclusive scan of 64 bins
        int v = cnt[t];
        int ex = v;
        #pragma unroll
        for (int d = 1; d < 64; d <<= 1) {
            int o = __shfl_up(ex, d);
            if (t >= d) ex += o;
        }
        beg[t] = ex - v;
        cnt[t] = ex - v;              // running cursor
    }
    __syncthreads();
    if (pk0 >= 0) eb[atomicAdd(&cnt[pk0 >> 16], 1)] = pk0 & 0xFFFF;
    if (pk1 >= 0) eb[atomicAdd(&cnt[pk1 >> 16], 1)] = pk1 & 0xFFFF;
    __syncthreads();                  // cnt[dl] now == end index
    // ---- per-node gather (edge ids in LDS) ----
    const int wv = t >> 6, lane = t & 63;
    const int slot = lane >> 4, j = lane & 15;
    const uint2* hw = (const uint2*)Hsrc;
    #pragma unroll
    for (int i = 0; i < 4; i++) {
        const int dl = wv * 4 + i;
        const int b0 = beg[dl], e1 = cnt[dl];
        float s0 = 0.f, s1 = 0.f, s2 = 0.f, s3 = 0.f;
        int e = b0;
        for (; e + 16 <= e1; e += 16) {
            int i0 = eb[e + slot];
            int i1 = eb[e + 4 + slot];
            int i2 = eb[e + 8 + slot];
            int i3 = eb[e + 12 + slot];
            uint2 u0 = hw[(size_t)i0 * 16 + j];
            uint2 u1 = hw[(size_t)i1 * 16 + j];
            uint2 u2 = hw[(size_t)i2 * 16 + j];
            uint2 u3 = hw[(size_t)i3 * 16 + j];
            float2 a, b;
            a = __half22float2(*(__half2*)&u0.x); b = __half22float2(*(__half2*)&u0.y);
            s0 += a.x; s1 += a.y; s2 += b.x; s3 += b.y;
            a = __half22float2(*(__half2*)&u1.x); b = __half22float2(*(__half2*)&u1.y);
            s0 += a.x; s1 += a.y; s2 += b.x; s3 += b.y;
            a = __half22float2(*(__half2*)&u2.x); b = __half22float2(*(__half2*)&u2.y);
            s0 += a.x; s1 += a.y; s2 += b.x; s3 += b.y;
            a = __half22float2(*(__half2*)&u3.x); b = __half22float2(*(__half2*)&u3.y);
            s0 += a.x; s1 += a.y; s2 += b.x; s3 += b.y;
        }
        for (; e + 4 <= e1; e += 4) {
            int i0 = eb[e + slot];
            uint2 u = hw[(size_t)i0 * 16 + j];
            float2 a = __half22float2(*(__half2*)&u.x);
            float2 b = __half22float2(*(__half2*)&u.y);
            s0 += a.x; s1 += a.y; s2 += b.x; s3 += b.y;
        }
        int rem = e1 - e;
        if (slot < rem) {
            int i0 = eb[e + slot];
            uint2 u = hw[(size_t)i0 * 16 + j];
            float2 a = __half22float2(*(__half2*)&u.x);
            float2 b = __half22float2(*(__half2*)&u.y);
            s0 += a.x; s1 += a.y; s2 += b.x; s3 += b.y;
        }
        s0 += __shfl_xor(s0, 16); s1 += __shfl_xor(s1, 16);
        s2 += __shfl_xor(s2, 16); s3 += __shfl_xor(s3, 16);
        s0 += __shfl_xor(s0, 32); s1 += __shfl_xor(s1, 32);
        s2 += __shfl_xor(s2, 32); s3 += __shfl_xor(s3, 32);
        if (slot == 0) {
            uint2 o; o.x = pack2h(s0, s1); o.y = pack2h(s2, s3);
            *(uint2*)((char*)Als + dl * 256 + ((128 + j * 8) ^ ((dl & 7) << 4))) = o;
        }
    }
    // x / W -> LDS (swizzled)
    *(uint2*)((char*)Als + cr * 256 + ((cj * 8) ^ ((cr & 7) << 4))) = xv;
    *(uint4*)((char*)Wls + cr * 256 + ((cj * 16) ^ ((cr & 7) << 4))) = wvv;
    __syncthreads();
    // MFMA: wave wv -> (wr, wc) 16x16 tile, k = 128
    const int lr = lane & 15, kh = lane >> 4;
    const int wr = wv >> 2, wc = wv & 3;
    const int arow = wr * 16 + lr;
    ncol = wc * 16 + lr;
    outrow0 = row0 + wr * 16 + kh * 4;
    float bv = bias[ncol];
    acc = (f32x4){bv, bv, bv, bv};
    #pragma unroll
    for (int kt = 0; kt < 4; kt++) {
        const int kb = (kt * 32 + kh * 8) * 2;
        f16x8 a = *(const f16x8*)((const char*)Als + arow * 256 + (kb ^ ((arow & 7) << 4)));
        f16x8 b = *(const f16x8*)((const char*)Wls + ncol * 256 + (kb ^ ((ncol & 7) << 4)));
        acc = __builtin_amdgcn_mfma_f32_16x16x32_f16(a, b, acc, 0, 0, 0);
    }
}

// ---------------- layer 1: sort + agg + GEMM -> h1 fp16 ----------------
__global__ __launch_bounds__(1024) void layer1_kernel(const f16_t* __restrict__ xh,
                                                      const int* __restrict__ epk,
                                                      const int* __restrict__ cur,
                                                      const f16_t* __restrict__ Wt,
                                                      const float* __restrict__ bias,
                                                      f16_t* __restrict__ h1h) {
    __shared__ f16_t Als[64 * 128];
    __shared__ f16_t Wls[64 * 128];
    __shared__ int eb[BKT_CAP];
    __shared__ int cnt[64];
    __shared__ int beg[64];
    const int t = threadIdx.x;
    const int blk = blockIdx.x;
    const int row0 = blk * 64;
    int n = cur[blk * CUR_STRIDE]; if (n > BKT_CAP) n = BKT_CAP;
    f32x4 acc; int ncol, outrow0;
    agg_stage_mfma(xh, epk + (size_t)blk * BKT_CAP, n, Wt, bias,
                   Als, Wls, eb, cnt, beg, row0, t, acc, ncol, outrow0);
    #pragma unroll
    for (int rr = 0; rr < 4; rr++) {
        const int gm = outrow0 + rr;
        if (gm < N_NODES)
            h1h[(size_t)gm * 64 + ncol] = (f16_t)fmaxf(acc[rr], 0.f);
    }
}

// ---------------- layer 2: sort + agg + GEMM + head + pooling + final ----------------
__global__ __launch_bounds__(1024) void layer2_head_kernel(
        const f16_t* __restrict__ h1h,
        const int* __restrict__ epk, const int* __restrict__ cur,
        const f16_t* __restrict__ Wt, const float* __restrict__ bias,
        const int* __restrict__ batch,
        const float* __restrict__ fc1w, const float* __restrict__ fc1b,
        const float* __restrict__ fc2w, const float* __restrict__ fc2b,
        float* __restrict__ mid_out, unsigned int* __restrict__ pooled,
        unsigned int* __restrict__ done_cnt, float* __restrict__ fin_out) {
    __shared__ f16_t Als[64 * 128];
    __shared__ f16_t Wls[64 * 128];
    __shared__ int eb[BKT_CAP];
    __shared__ int cnt[64];
    __shared__ int beg[64];
    __shared__ float tile[64 * 65];
    __shared__ float w1s[512];
    __shared__ float z1s[64 * 9];
    __shared__ float b1s[8];
    __shared__ float w2s[16];
    __shared__ float b2s[2];
    __shared__ unsigned int pool_s[N_GRAPHS * 2];
    __shared__ unsigned int amLast;
    __shared__ float fin[N_GRAPHS * 2];
    const int t = threadIdx.x;
    const int blk = blockIdx.x;
    const int row0 = blk * 64;
    if (t < 512) w1s[t] = fc1w[t];
    if (t >= 512 && t < 520) b1s[t - 512] = fc1b[t - 512];
    if (t >= 520 && t < 536) w2s[t - 520] = fc2w[t - 520];
    if (t >= 536 && t < 538) b2s[t - 536] = fc2b[t - 536];
    if (t >= 544 && t < 544 + N_GRAPHS * 2) pool_s[t - 544] = 0u;
    int n = cur[blk * CUR_STRIDE]; if (n > BKT_CAP) n = BKT_CAP;
    f32x4 acc; int ncol, outrow0;
    agg_stage_mfma(h1h, epk + (size_t)blk * BKT_CAP, n, Wt, bias,
                   Als, Wls, eb, cnt, beg, row0, t, acc, ncol, outrow0);
    #pragma unroll
    for (int rr = 0; rr < 4; rr++)
        tile[(outrow0 - row0 + rr) * 65 + ncol] = fmaxf(acc[rr], 0.f);
    __syncthreads();
    const int row = t & 63, qq = t >> 6;
    const int gm = row0 + row;
    const bool valid = gm < N_NODES;
    if (qq < 4) {
        float z0 = b1s[2 * qq], z1v = b1s[2 * qq + 1];
        for (int k = 0; k < 64; k++) {
            float a = tile[row * 65 + k];
            z0  += a * w1s[k * 8 + 2 * qq];
            z1v += a * w1s[k * 8 + 2 * qq + 1];
        }
        z1s[row * 9 + 2 * qq]     = fmaxf(z0, 0.f);
        z1s[row * 9 + 2 * qq + 1] = fmaxf(z1v, 0.f);
    }
    if (qq == 4 && valid) {   // mid softmax (wave group 4, overlaps fc1)
        float rv[8];
        #pragma unroll
        for (int c = 0; c < 8; c++) rv[c] = tile[row * 65 + c];
        float m = rv[0];
        #pragma unroll
        for (int c = 1; c < 8; c++) m = fmaxf(m, rv[c]);
        float ex[8], s = 0.f;
        #pragma unroll
        for (int c = 0; c < 8; c++) { ex[c] = __expf(rv[c] - m); s += ex[c]; }
        float inv = 1.f / s;
        float4 v0 = {ex[0] * inv, ex[1] * inv, ex[2] * inv, ex[3] * inv};
        float4 v1 = {ex[4] * inv, ex[5] * inv, ex[6] * inv, ex[7] * inv};
        *(float4*)&mid_out[(size_t)gm * 8]     = v0;
        *(float4*)&mid_out[(size_t)gm * 8 + 4] = v1;
    }
    __syncthreads();
    if (qq == 0 && valid) {   // fc2 + LDS pool
        float z20 = b2s[0], z21 = b2s[1];
        #pragma unroll
        for (int o = 0; o < 8; o++) {
            float z = z1s[row * 9 + o];
            z20 += z * w2s[o * 2];
            z21 += z * w2s[o * 2 + 1];
        }
        z20 = fmaxf(z20, 0.f);
        z21 = fmaxf(z21, 0.f);
        int b = batch[gm];
        atomicMax(&pool_s[b * 2 + 0], __float_as_uint(z20));
        atomicMax(&pool_s[b * 2 + 1], __float_as_uint(z21));
    }
    __syncthreads();
    if (t < N_GRAPHS * 2) {
        unsigned int v = pool_s[t];
        if (v) atomicMax(&pooled[t], v);
    }
    __syncthreads();
    if (t == 0) {
        __threadfence();
        unsigned int prev = atomicAdd(done_cnt, 1u);
        amLast = (prev == gridDim.x - 1) ? 1u : 0u;
    }
    __syncthreads();
    if (amLast) {
        if (t < N_GRAPHS * 2) fin[t] = __uint_as_float(atomicMax(&pooled[t], 0u));
        __syncthreads();
        if (t < N_GRAPHS) {
            float v0 = fin[2 * t], v1 = fin[2 * t + 1];
            float m = fmaxf(v0, v1);
            float e0 = __expf(v0 - m), e1 = __expf(v1 - m);
            float s = e0 + e1;
            fin_out[2 * t]     = e0 / s;
            fin_out[2 * t + 1] = e1 / s;
        }
    }
}

// ---------------- launch ----------------
extern "C" void kernel_launch(void* const* d_in, const int* in_sizes, int n_in,
                              void* d_out, int out_size, void* d_ws, size_t ws_size,
                              hipStream_t stream) {
    const float* x    = (const float*)d_in[0];
    const int*   ei   = (const int*)d_in[1];
    const int*   batch= (const int*)d_in[2];
    const float* W1r  = (const float*)d_in[3];
    const float* W1l  = (const float*)d_in[4];
    const float* b1   = (const float*)d_in[5];
    const float* W2r  = (const float*)d_in[6];
    const float* W2l  = (const float*)d_in[7];
    const float* b2   = (const float*)d_in[8];
    const float* fc1w = (const float*)d_in[9];
    const float* fc1b = (const float*)d_in[10];
    const float* fc2w = (const float*)d_in[11];
    const float* fc2b = (const float*)d_in[12];

    const int* src = ei;
    const int* dst = ei + N_EDGES;

    char* ws = (char*)d_ws;
    int*    cur    = (int*)(ws + OFF_CUR);
    unsigned int* pooled   = (unsigned int*)(ws + OFF_POOLED);
    unsigned int* done_cnt = (unsigned int*)(ws + OFF_DONE);
    int*    epk    = (int*)(ws + OFF_EPK);
    f16_t*  xh     = (f16_t*)(ws + OFF_XH);
    f16_t*  h1h    = (f16_t*)(ws + OFF_H1H);
    f16_t*  Wt1    = (f16_t*)(ws + OFF_WT1);
    f16_t*  Wt2    = (f16_t*)(ws + OFF_WT2);

    float* mid_out = (float*)d_out;                       // 50000*8
    float* fin_out = (float*)d_out + (size_t)N_NODES * 8; // 64*2

    init_cast_wcast_kernel<<<CAST_BLKS + 2, 256, 0, stream>>>(
        x, xh, W1r, W1l, Wt1, W2r, W2l, Wt2, cur, pooled, done_cnt);
    hist_scatter_kernel<<<HS_BLOCKS, 256, 0, stream>>>(src, dst, cur, epk);

    layer1_kernel<<<NBKT, 1024, 0, stream>>>(xh, epk, cur, Wt1, b1, h1h);
    layer2_head_kernel<<<NBKT, 1024, 0, stream>>>(h1h, epk, cur, Wt2, b2, batch,
                                                  fc1w, fc1b, fc2w, fc2b,
                                                  mid_out, pooled, done_cnt, fin_out);
}